// Round 1
// baseline (274.222 us; speedup 1.0000x reference)
//
#include <hip/hip_runtime.h>
#include <hip/hip_bf16.h>
#include <math.h>

// Problem constants
#define N_TOK 196
#define C_DIM 480
#define M_KV  23520      // (C/4)*N
#define EPSN  1e-3f

// Workspace layout (in floats)
#define OFF_QC    0
#define OFF_KC    94080
#define OFF_VC    188160
#define OFF_ATTN  282240   // 480*480, becomes sim in-place
#define OFF_THAT  512640   // 196*480
#define OFF_KV    606720   // float2[4*23520] = 188160 floats
#define OFF_BTAB  794880   // 16*196
#define OFF_MTAB  798016   // 16*196
#define OFF_LACC  801152   // 16*196 (zeroed)
#define OFF_CACC  804288   // 16*196 (zeroed)
#define OFF_S1    807424   // sum, sumsq of attn (zeroed)
#define OFF_HS    807426   // per-head sum K (zeroed)
#define OFF_HSQ   807430   // per-head sum K^2 (zeroed)
#define OFF_MAXE  807434   // per-head ordered-uint max enc (zeroed)
#define OFF_NEGE  807438   // per-head ordered-uint max enc of -K (zeroed)
#define ZERO_OFF  OFF_LACC
#define ZERO_CNT  (807442 - OFF_LACC)

__device__ __forceinline__ unsigned enc_f(float x) {
    unsigned b = __float_as_uint(x);
    return (b & 0x80000000u) ? ~b : (b | 0x80000000u);
}
__device__ __forceinline__ float dec_f(unsigned u) {
    unsigned b = (u & 0x80000000u) ? (u & 0x7FFFFFFFu) : ~u;
    return __uint_as_float(b);
}

// ---------------- K1: Qc/Kc/Vc = emb_C @ {Wq_C,Wk_C,Wv_C} ----------------
__global__ __launch_bounds__(256) void k_qkv(const float* __restrict__ embC,
                                             const float* __restrict__ Wq,
                                             const float* __restrict__ Wk,
                                             const float* __restrict__ Wv,
                                             float* __restrict__ ws) {
    int zi = blockIdx.z;
    const float* W = (zi == 0) ? Wq : (zi == 1 ? Wk : Wv);
    float* out = ws + zi * 94080;
    __shared__ float As[32][17];
    __shared__ float Bs[16][32];
    int tid = threadIdx.x;
    int m0 = blockIdx.y * 32, n0 = blockIdx.x * 32;
    int ty = tid >> 4, tx = tid & 15;
    float a00 = 0, a01 = 0, a10 = 0, a11 = 0;
    for (int k0 = 0; k0 < 480; k0 += 16) {
        #pragma unroll
        for (int it = 0; it < 2; ++it) {
            int idx = tid + it * 256; int r = idx >> 4, c = idx & 15;
            int m = m0 + r;
            As[r][c] = (m < N_TOK) ? embC[m * 480 + k0 + c] : 0.f;
        }
        #pragma unroll
        for (int it = 0; it < 2; ++it) {
            int idx = tid + it * 256; int r = idx >> 5, c = idx & 31;
            Bs[r][c] = W[(k0 + r) * 480 + n0 + c];
        }
        __syncthreads();
        #pragma unroll
        for (int kk = 0; kk < 16; ++kk) {
            float x0 = As[ty * 2][kk], x1 = As[ty * 2 + 1][kk];
            float b0 = Bs[kk][tx * 2], b1 = Bs[kk][tx * 2 + 1];
            a00 = fmaf(x0, b0, a00); a01 = fmaf(x0, b1, a01);
            a10 = fmaf(x1, b0, a10); a11 = fmaf(x1, b1, a11);
        }
        __syncthreads();
    }
    int m = m0 + ty * 2, n = n0 + tx * 2;
    if (m < N_TOK)     { out[m * 480 + n] = a00; out[m * 480 + n + 1] = a01; }
    if (m + 1 < N_TOK) { out[(m + 1) * 480 + n] = a10; out[(m + 1) * 480 + n + 1] = a11; }
}

// ---------------- K2: attn = Qc^T @ Kc  (+ global sum/sumsq) ----------------
__global__ __launch_bounds__(256) void k_attn(const float* __restrict__ Qc,
                                              const float* __restrict__ Kc,
                                              float* __restrict__ attn,
                                              float* __restrict__ s1) {
    __shared__ float As[32][17];   // As[c_local][n_local]
    __shared__ float Bs[16][32];   // Bs[n_local][d_local]
    __shared__ float sha[4], shb[4];
    int tid = threadIdx.x;
    int c0 = blockIdx.y * 32, d0 = blockIdx.x * 32;
    int ty = tid >> 4, tx = tid & 15;
    float a00 = 0, a01 = 0, a10 = 0, a11 = 0;
    for (int k0 = 0; k0 < 196; k0 += 16) {
        #pragma unroll
        for (int it = 0; it < 2; ++it) {
            int idx = tid + it * 256; int cc = idx & 31, nn = idx >> 5;
            int n = k0 + nn;
            As[cc][nn] = (n < N_TOK) ? Qc[n * 480 + c0 + cc] : 0.f;
        }
        #pragma unroll
        for (int it = 0; it < 2; ++it) {
            int idx = tid + it * 256; int nn = idx >> 5, dd = idx & 31;
            int n = k0 + nn;
            Bs[nn][dd] = (n < N_TOK) ? Kc[n * 480 + d0 + dd] : 0.f;
        }
        __syncthreads();
        #pragma unroll
        for (int kk = 0; kk < 16; ++kk) {
            float x0 = As[ty * 2][kk], x1 = As[ty * 2 + 1][kk];
            float b0 = Bs[kk][tx * 2], b1 = Bs[kk][tx * 2 + 1];
            a00 = fmaf(x0, b0, a00); a01 = fmaf(x0, b1, a01);
            a10 = fmaf(x1, b0, a10); a11 = fmaf(x1, b1, a11);
        }
        __syncthreads();
    }
    int c = c0 + ty * 2, d = d0 + tx * 2;
    attn[c * 480 + d] = a00;       attn[c * 480 + d + 1] = a01;
    attn[(c + 1) * 480 + d] = a10; attn[(c + 1) * 480 + d + 1] = a11;
    // stats
    float ls = a00 + a01 + a10 + a11;
    float lq = a00 * a00 + a01 * a01 + a10 * a10 + a11 * a11;
    #pragma unroll
    for (int o = 32; o > 0; o >>= 1) { ls += __shfl_xor(ls, o, 64); lq += __shfl_xor(lq, o, 64); }
    int wid = tid >> 6, lane = tid & 63;
    if (lane == 0) { sha[wid] = ls; shb[wid] = lq; }
    __syncthreads();
    if (tid == 0) {
        atomicAdd(s1,     sha[0] + sha[1] + sha[2] + sha[3]);
        atomicAdd(s1 + 1, shb[0] + shb[1] + shb[2] + shb[3]);
    }
}

// ---------------- K3: per-row softmax of attn * s1 ----------------
__global__ __launch_bounds__(256) void k_softmax(float* __restrict__ attn,
                                                 const float* __restrict__ s1,
                                                 const float* __restrict__ g1) {
    int c = blockIdx.x;
    int tid = threadIdx.x;
    __shared__ float shm[4], shs[4];
    const float invCC = 1.f / (480.f * 480.f);
    float mean = s1[0] * invCC;
    float var  = s1[1] * invCC - mean * mean;
    float s = g1[0] * rsqrtf(var + EPSN);
    float y0 = attn[c * 480 + tid] * s;
    bool v1 = tid < 224;
    float y1 = v1 ? attn[c * 480 + tid + 256] * s : -INFINITY;
    float mx = fmaxf(y0, y1);
    #pragma unroll
    for (int o = 32; o > 0; o >>= 1) mx = fmaxf(mx, __shfl_xor(mx, o, 64));
    int wid = tid >> 6, lane = tid & 63;
    if (lane == 0) shm[wid] = mx;
    __syncthreads();
    mx = fmaxf(fmaxf(shm[0], shm[1]), fmaxf(shm[2], shm[3]));
    float e0 = __expf(y0 - mx);
    float e1 = v1 ? __expf(y1 - mx) : 0.f;
    float sm = e0 + e1;
    #pragma unroll
    for (int o = 32; o > 0; o >>= 1) sm += __shfl_xor(sm, o, 64);
    if (lane == 0) shs[wid] = sm;
    __syncthreads();
    sm = shs[0] + shs[1] + shs[2] + shs[3];
    float inv = 1.f / sm;
    attn[c * 480 + tid] = e0 * inv;
    if (v1) attn[c * 480 + tid + 256] = e1 * inv;
}

// ---------------- K4: T_hat = Vc @ sim^T ----------------
__global__ __launch_bounds__(256) void k_that(const float* __restrict__ Vc,
                                              const float* __restrict__ sim,
                                              float* __restrict__ That) {
    __shared__ float As[32][17];   // Vc[n][d] tile
    __shared__ float Bs[16][33];   // Bs[d_local][c_local]
    int tid = threadIdx.x;
    int c0 = blockIdx.x * 32, n0 = blockIdx.y * 32;
    int ty = tid >> 4, tx = tid & 15;
    float a00 = 0, a01 = 0, a10 = 0, a11 = 0;
    for (int d0 = 0; d0 < 480; d0 += 16) {
        #pragma unroll
        for (int it = 0; it < 2; ++it) {
            int idx = tid + it * 256; int r = idx >> 4, c = idx & 15;
            int n = n0 + r;
            As[r][c] = (n < N_TOK) ? Vc[n * 480 + d0 + c] : 0.f;
        }
        #pragma unroll
        for (int it = 0; it < 2; ++it) {
            int idx = tid + it * 256; int dd = idx & 15, cc = idx >> 4;
            Bs[dd][cc] = sim[(c0 + cc) * 480 + d0 + dd];
        }
        __syncthreads();
        #pragma unroll
        for (int kk = 0; kk < 16; ++kk) {
            float x0 = As[ty * 2][kk], x1 = As[ty * 2 + 1][kk];
            float b0 = Bs[kk][tx * 2], b1 = Bs[kk][tx * 2 + 1];
            a00 = fmaf(x0, b0, a00); a01 = fmaf(x0, b1, a01);
            a10 = fmaf(x1, b0, a10); a11 = fmaf(x1, b1, a11);
        }
        __syncthreads();
    }
    int n = n0 + ty * 2, c = c0 + tx * 2;
    if (n < N_TOK)     { That[n * 480 + c] = a00; That[n * 480 + c + 1] = a01; }
    if (n + 1 < N_TOK) { That[(n + 1) * 480 + c] = a10; That[(n + 1) * 480 + c + 1] = a11; }
}

// ---------------- K5a: K/V projection + per-head stats ----------------
__global__ __launch_bounds__(256) void k_kv(const float* __restrict__ That,
                                            const float* __restrict__ Wk,
                                            const float* __restrict__ Wv,
                                            float2* __restrict__ KV,
                                            float* __restrict__ hs,
                                            float* __restrict__ hsq,
                                            unsigned* __restrict__ maxe,
                                            unsigned* __restrict__ nege) {
    int m = blockIdx.x * 256 + threadIdx.x;
    bool act = m < M_KV;
    int n = act ? (m % 196) : 0;
    int j = act ? (m / 196) : 0;
    float4 th = act ? *(const float4*)(That + n * 480 + 4 * j) : make_float4(0, 0, 0, 0);
    int lane = threadIdx.x & 63;
    #pragma unroll
    for (int h = 0; h < 4; ++h) {
        float kh = th.x * Wk[h] + th.y * Wk[4 + h] + th.z * Wk[8 + h] + th.w * Wk[12 + h];
        float vh = th.x * Wv[h] + th.y * Wv[4 + h] + th.z * Wv[8 + h] + th.w * Wv[12 + h];
        if (act) KV[h * M_KV + m] = make_float2(kh, vh);
        float su = act ? kh : 0.f;
        float sq = act ? kh * kh : 0.f;
        float mx = act ? kh : -INFINITY;
        float nm = act ? -kh : -INFINITY;
        #pragma unroll
        for (int o = 32; o > 0; o >>= 1) {
            su += __shfl_xor(su, o, 64);
            sq += __shfl_xor(sq, o, 64);
            mx = fmaxf(mx, __shfl_xor(mx, o, 64));
            nm = fmaxf(nm, __shfl_xor(nm, o, 64));
        }
        if (lane == 0) {
            atomicAdd(hs + h, su);
            atomicAdd(hsq + h, sq);
            atomicMax(maxe + h, enc_f(mx));
            atomicMax(nege + h, enc_f(nm));
        }
    }
}

// ---------------- K5b: per-(branch,head) beta table + analytic row max ----------------
__global__ __launch_bounds__(256) void k_qstats(const float* __restrict__ e0, const float* __restrict__ e1,
                                                const float* __restrict__ e2, const float* __restrict__ e3,
                                                const float* __restrict__ w0, const float* __restrict__ w1,
                                                const float* __restrict__ w2, const float* __restrict__ w3,
                                                const float* __restrict__ g2v,
                                                const float* __restrict__ hs, const float* __restrict__ hsq,
                                                const unsigned* __restrict__ maxe, const unsigned* __restrict__ nege,
                                                float* __restrict__ Btab, float* __restrict__ Mtab) {
    int rowid = blockIdx.x;
    int i = rowid >> 2, h = rowid & 3;
    const float* emb = (i == 0) ? e0 : (i == 1) ? e1 : (i == 2) ? e2 : e3;
    const float* Wq  = (i == 0) ? w0 : (i == 1) ? w1 : (i == 2) ? w2 : w3;
    int q = threadIdx.x;
    bool act = q < 196;
    float Q = 0.f;
    if (act) {
        Q = emb[q * 4] * Wq[h] + emb[q * 4 + 1] * Wq[4 + h] +
            emb[q * 4 + 2] * Wq[8 + h] + emb[q * 4 + 3] * Wq[12 + h];
    }
    float s = act ? Q : 0.f, s2 = act ? Q * Q : 0.f;
    #pragma unroll
    for (int o = 32; o > 0; o >>= 1) { s += __shfl_xor(s, o, 64); s2 += __shfl_xor(s2, o, 64); }
    __shared__ float shs[4], shs2[4];
    int wid = threadIdx.x >> 6, lane = threadIdx.x & 63;
    if (lane == 0) { shs[wid] = s; shs2[wid] = s2; }
    __syncthreads();
    float sumQ  = shs[0] + shs[1] + shs[2] + shs[3];
    float sumQ2 = shs2[0] + shs2[1] + shs2[2] + shs2[3];
    float Qbar = sumQ * (1.f / 196.f), Q2bar = sumQ2 * (1.f / 196.f);
    float Kbar = hs[h] * (1.f / (float)M_KV), K2bar = hsq[h] * (1.f / (float)M_KV);
    float mu = Qbar * Kbar;
    float var = Q2bar * K2bar - mu * mu;
    float sc = g2v[h] * rsqrtf(var + EPSN);
    float Kmax = dec_f(maxe[h]);
    float Kmin = -dec_f(nege[h]);
    if (act) {
        float b = Q * sc;
        Btab[rowid * 196 + q] = b;
        Mtab[rowid * 196 + q] = (b >= 0.f) ? b * Kmax : b * Kmin;
    }
}

// ---------------- K6: branch attention, split-k exp reduction ----------------
#define KCHUNK 1470
__global__ __launch_bounds__(256) void k_branch(const float2* __restrict__ KV,
                                                const float* __restrict__ Btab,
                                                const float* __restrict__ Mtab,
                                                float* __restrict__ Lacc,
                                                float* __restrict__ Cacc) {
    int row = blockIdx.y;        // 0..15 : i*4 + h
    int h = row & 3;
    int chunk = blockIdx.x;      // 0..15
    __shared__ float2 kv[KCHUNK];
    const float2* src = KV + h * M_KV + chunk * KCHUNK;
    for (int idx = threadIdx.x; idx < KCHUNK; idx += 256) kv[idx] = src[idx];
    __syncthreads();
    int wid = threadIdx.x >> 6, lane = threadIdx.x & 63;
    for (int q = wid; q < 196; q += 4) {
        float beta = Btab[row * 196 + q];
        float Mq   = Mtab[row * 196 + q];
        float l = 0.f, a = 0.f;
        for (int k = lane; k < KCHUNK; k += 64) {
            float2 p = kv[k];
            float x = __expf(fmaf(beta, p.x, -Mq));
            l += x;
            a = fmaf(x, p.y, a);
        }
        #pragma unroll
        for (int o = 32; o > 0; o >>= 1) { l += __shfl_xor(l, o, 64); a += __shfl_xor(a, o, 64); }
        if (lane == 0) {
            atomicAdd(Lacc + row * 196 + q, l);
            atomicAdd(Cacc + row * 196 + q, a);
        }
    }
}

// ---------------- K7: finalize: c = acc/l, out = c @ Wo ----------------
__global__ __launch_bounds__(256) void k_final(const float* __restrict__ Lacc,
                                               const float* __restrict__ Cacc,
                                               const float* __restrict__ o0, const float* __restrict__ o1,
                                               const float* __restrict__ o2, const float* __restrict__ o3,
                                               float* __restrict__ out) {
    int i = blockIdx.x;
    int q = threadIdx.x;
    if (q >= 196) return;
    const float* Wo = (i == 0) ? o0 : (i == 1) ? o1 : (i == 2) ? o2 : o3;
    float c[4];
    #pragma unroll
    for (int h = 0; h < 4; ++h) {
        int idx = (i * 4 + h) * 196 + q;
        c[h] = Cacc[idx] / Lacc[idx];
    }
    float4 o;
    o.x = c[0] * Wo[0] + c[1] * Wo[4] + c[2] * Wo[8]  + c[3] * Wo[12];
    o.y = c[0] * Wo[1] + c[1] * Wo[5] + c[2] * Wo[9]  + c[3] * Wo[13];
    o.z = c[0] * Wo[2] + c[1] * Wo[6] + c[2] * Wo[10] + c[3] * Wo[14];
    o.w = c[0] * Wo[3] + c[1] * Wo[7] + c[2] * Wo[11] + c[3] * Wo[15];
    *(float4*)(out + i * 784 + q * 4) = o;
}

extern "C" void kernel_launch(void* const* d_in, const int* in_sizes, int n_in,
                              void* d_out, int out_size, void* d_ws, size_t ws_size,
                              hipStream_t stream) {
    const float* emb1 = (const float*)d_in[0];
    const float* emb2 = (const float*)d_in[1];
    const float* emb3 = (const float*)d_in[2];
    const float* emb4 = (const float*)d_in[3];
    const float* embC = (const float*)d_in[4];
    const float* WqC  = (const float*)d_in[5];
    const float* WkC  = (const float*)d_in[6];
    const float* WvC  = (const float*)d_in[7];
    const float* Wq1  = (const float*)d_in[8];
    const float* Wq2  = (const float*)d_in[9];
    const float* Wq3  = (const float*)d_in[10];
    const float* Wq4  = (const float*)d_in[11];
    const float* Wk   = (const float*)d_in[12];
    const float* Wv   = (const float*)d_in[13];
    const float* Wo1  = (const float*)d_in[14];
    const float* Wo2  = (const float*)d_in[15];
    const float* Wo3  = (const float*)d_in[16];
    const float* Wo4  = (const float*)d_in[17];
    const float* g1   = (const float*)d_in[18];
    const float* g2   = (const float*)d_in[20];
    float* ws = (float*)d_ws;
    float* out = (float*)d_out;

    // zero the accumulator region (ws is poisoned 0xAA and not re-poisoned between replays)
    hipMemsetAsync(ws + ZERO_OFF, 0, ZERO_CNT * sizeof(float), stream);

    k_qkv<<<dim3(15, 7, 3), 256, 0, stream>>>(embC, WqC, WkC, WvC, ws);
    k_attn<<<dim3(15, 15), 256, 0, stream>>>(ws + OFF_QC, ws + OFF_KC, ws + OFF_ATTN, ws + OFF_S1);
    k_softmax<<<480, 256, 0, stream>>>(ws + OFF_ATTN, ws + OFF_S1, g1);
    k_that<<<dim3(15, 7), 256, 0, stream>>>(ws + OFF_VC, ws + OFF_ATTN, ws + OFF_THAT);
    k_kv<<<92, 256, 0, stream>>>(ws + OFF_THAT, Wk, Wv, (float2*)(ws + OFF_KV),
                                 ws + OFF_HS, ws + OFF_HSQ,
                                 (unsigned*)(ws + OFF_MAXE), (unsigned*)(ws + OFF_NEGE));
    k_qstats<<<16, 256, 0, stream>>>(emb1, emb2, emb3, emb4, Wq1, Wq2, Wq3, Wq4, g2,
                                     ws + OFF_HS, ws + OFF_HSQ,
                                     (const unsigned*)(ws + OFF_MAXE), (const unsigned*)(ws + OFF_NEGE),
                                     ws + OFF_BTAB, ws + OFF_MTAB);
    k_branch<<<dim3(16, 16), 256, 0, stream>>>((const float2*)(ws + OFF_KV),
                                               ws + OFF_BTAB, ws + OFF_MTAB,
                                               ws + OFF_LACC, ws + OFF_CACC);
    k_final<<<4, 256, 0, stream>>>(ws + OFF_LACC, ws + OFF_CACC, Wo1, Wo2, Wo3, Wo4, out);
}

// Round 2
// 188.021 us; speedup vs baseline: 1.4585x; 1.4585x over previous
//
#include <hip/hip_runtime.h>
#include <hip/hip_bf16.h>
#include <math.h>

// Problem constants
#define N_TOK 196
#define C_DIM 480
#define M_KV  23520      // (C/4)*N
#define EPSN  1e-3f

// Workspace layout (in floats)
#define OFF_QC    0
#define OFF_KC    94080
#define OFF_VC    188160
#define OFF_ATTN  282240   // 480*480, becomes sim in-place
#define OFF_THAT  512640   // 196*480
#define OFF_KV    606720   // float2[4*23520] = 188160 floats
#define OFF_BTAB  794880   // 16*196
#define OFF_MTAB  798016   // 16*196
#define OFF_LACC  801152   // 16*196 (zeroed)
#define OFF_CACC  804288   // 16*196 (zeroed)
#define OFF_S1    807424   // sum, sumsq of attn (zeroed)
#define OFF_HS    807426   // per-head sum K (zeroed)
#define OFF_HSQ   807430   // per-head sum K^2 (zeroed)
#define OFF_MAXE  807434   // per-head ordered-uint max enc (zeroed)
#define OFF_NEGE  807438   // per-head ordered-uint max enc of -K (zeroed)
#define ZERO_OFF  OFF_LACC
#define ZERO_CNT  (807442 - OFF_LACC)

__device__ __forceinline__ unsigned enc_f(float x) {
    unsigned b = __float_as_uint(x);
    return (b & 0x80000000u) ? ~b : (b | 0x80000000u);
}
__device__ __forceinline__ float dec_f(unsigned u) {
    unsigned b = (u & 0x80000000u) ? (u & 0x7FFFFFFFu) : ~u;
    return __uint_as_float(b);
}

// ============ GEMM tiles: 64 (M) x 32 (N), 256 threads, 4x2 per thread ======
// As[kk][m]: 16 x 64 (+4 pad), Bs[kk][n]: 16 x 32 (+4 pad)

// ---------------- K1: Qc/Kc/Vc = emb_C @ {Wq_C,Wk_C,Wv_C} ----------------
// M=196 (mask rows), N=480 (exact 15 tiles), K=480 (30 steps)
__global__ __launch_bounds__(256) void k_qkv(const float* __restrict__ embC,
                                             const float* __restrict__ Wq,
                                             const float* __restrict__ Wk,
                                             const float* __restrict__ Wv,
                                             float* __restrict__ ws) {
    int zi = blockIdx.z;
    const float* W = (zi == 0) ? Wq : (zi == 1 ? Wk : Wv);
    float* out = ws + zi * 94080;
    __shared__ float As[16][68];
    __shared__ float Bs[16][36];
    int tid = threadIdx.x;
    int n0 = blockIdx.x * 32, m0 = blockIdx.y * 64;
    int ty = tid >> 4, tx = tid & 15;
    float a00=0,a01=0,a10=0,a11=0,a20=0,a21=0,a30=0,a31=0;
    int mrow = tid >> 2, kq = (tid & 3) * 4;
    for (int k0 = 0; k0 < 480; k0 += 16) {
        // A: embC rows -> transposed into As
        {
            int m = m0 + mrow;
            float4 v = make_float4(0,0,0,0);
            if (m < N_TOK) v = *(const float4*)(embC + m*480 + k0 + kq);
            As[kq+0][mrow] = v.x; As[kq+1][mrow] = v.y;
            As[kq+2][mrow] = v.z; As[kq+3][mrow] = v.w;
        }
        // B: W direct
        if (tid < 128) {
            int kk = tid >> 3, nq = (tid & 7) * 4;
            float4 v = *(const float4*)(W + (k0+kk)*480 + n0 + nq);
            *(float4*)&Bs[kk][nq] = v;
        }
        __syncthreads();
        #pragma unroll
        for (int kk = 0; kk < 16; ++kk) {
            float4 av = *(const float4*)&As[kk][ty*4];
            float2 bv = *(const float2*)&Bs[kk][tx*2];
            a00 = fmaf(av.x, bv.x, a00); a01 = fmaf(av.x, bv.y, a01);
            a10 = fmaf(av.y, bv.x, a10); a11 = fmaf(av.y, bv.y, a11);
            a20 = fmaf(av.z, bv.x, a20); a21 = fmaf(av.z, bv.y, a21);
            a30 = fmaf(av.w, bv.x, a30); a31 = fmaf(av.w, bv.y, a31);
        }
        __syncthreads();
    }
    int m = m0 + ty*4, n = n0 + tx*2;
    if (m   < N_TOK) *(float2*)(out + (m  )*480 + n) = make_float2(a00, a01);
    if (m+1 < N_TOK) *(float2*)(out + (m+1)*480 + n) = make_float2(a10, a11);
    if (m+2 < N_TOK) *(float2*)(out + (m+2)*480 + n) = make_float2(a20, a21);
    if (m+3 < N_TOK) *(float2*)(out + (m+3)*480 + n) = make_float2(a30, a31);
}

// ---------------- K2: attn = Qc^T @ Kc  (+ global sum/sumsq) ----------------
// M=480 (8 tiles of 64, mask), N=480 (15 tiles), K=196 (13 steps, zero-fill tail)
__global__ __launch_bounds__(256) void k_attn(const float* __restrict__ Qc,
                                              const float* __restrict__ Kc,
                                              float* __restrict__ attn,
                                              float* __restrict__ s1) {
    __shared__ float As[16][68];
    __shared__ float Bs[16][36];
    __shared__ float sha[4], shb[4];
    int tid = threadIdx.x;
    int n0 = blockIdx.x * 32, m0 = blockIdx.y * 64;
    int ty = tid >> 4, tx = tid & 15;
    float a00=0,a01=0,a10=0,a11=0,a20=0,a21=0,a30=0,a31=0;
    for (int k0 = 0; k0 < 208; k0 += 16) {
        // A: Qc^T is already [n][c]; As[kk][m] = Qc[(k0+kk)*480 + m0+m]
        {
            int kk = tid >> 4, mq = (tid & 15) * 4;
            float4 v = make_float4(0,0,0,0);
            if (k0+kk < N_TOK && m0+mq < 480)
                v = *(const float4*)(Qc + (k0+kk)*480 + m0 + mq);
            *(float4*)&As[kk][mq] = v;
        }
        if (tid < 128) {
            int kk = tid >> 3, nq = (tid & 7) * 4;
            float4 v = make_float4(0,0,0,0);
            if (k0+kk < N_TOK) v = *(const float4*)(Kc + (k0+kk)*480 + n0 + nq);
            *(float4*)&Bs[kk][nq] = v;
        }
        __syncthreads();
        #pragma unroll
        for (int kk = 0; kk < 16; ++kk) {
            float4 av = *(const float4*)&As[kk][ty*4];
            float2 bv = *(const float2*)&Bs[kk][tx*2];
            a00 = fmaf(av.x, bv.x, a00); a01 = fmaf(av.x, bv.y, a01);
            a10 = fmaf(av.y, bv.x, a10); a11 = fmaf(av.y, bv.y, a11);
            a20 = fmaf(av.z, bv.x, a20); a21 = fmaf(av.z, bv.y, a21);
            a30 = fmaf(av.w, bv.x, a30); a31 = fmaf(av.w, bv.y, a31);
        }
        __syncthreads();
    }
    int m = m0 + ty*4, n = n0 + tx*2;
    if (m   < 480) *(float2*)(attn + (m  )*480 + n) = make_float2(a00, a01);
    if (m+1 < 480) *(float2*)(attn + (m+1)*480 + n) = make_float2(a10, a11);
    if (m+2 < 480) *(float2*)(attn + (m+2)*480 + n) = make_float2(a20, a21);
    if (m+3 < 480) *(float2*)(attn + (m+3)*480 + n) = make_float2(a30, a31);
    // stats (zero-padded OOB elements contribute 0)
    float ls = a00+a01+a10+a11+a20+a21+a30+a31;
    float lq = a00*a00+a01*a01+a10*a10+a11*a11+a20*a20+a21*a21+a30*a30+a31*a31;
    #pragma unroll
    for (int o = 32; o > 0; o >>= 1) { ls += __shfl_xor(ls, o, 64); lq += __shfl_xor(lq, o, 64); }
    int wid = tid >> 6, lane = tid & 63;
    if (lane == 0) { sha[wid] = ls; shb[wid] = lq; }
    __syncthreads();
    if (tid == 0) {
        atomicAdd(s1,     sha[0] + sha[1] + sha[2] + sha[3]);
        atomicAdd(s1 + 1, shb[0] + shb[1] + shb[2] + shb[3]);
    }
}

// ---------------- K3: per-row softmax of attn * s1 ----------------
__global__ __launch_bounds__(256) void k_softmax(float* __restrict__ attn,
                                                 const float* __restrict__ s1,
                                                 const float* __restrict__ g1) {
    int c = blockIdx.x;
    int tid = threadIdx.x;
    __shared__ float shm[4], shs[4];
    const float invCC = 1.f / (480.f * 480.f);
    float mean = s1[0] * invCC;
    float var  = s1[1] * invCC - mean * mean;
    float s = g1[0] * rsqrtf(var + EPSN);
    float y0 = attn[c * 480 + tid] * s;
    bool v1 = tid < 224;
    float y1 = v1 ? attn[c * 480 + tid + 256] * s : -INFINITY;
    float mx = fmaxf(y0, y1);
    #pragma unroll
    for (int o = 32; o > 0; o >>= 1) mx = fmaxf(mx, __shfl_xor(mx, o, 64));
    int wid = tid >> 6, lane = tid & 63;
    if (lane == 0) shm[wid] = mx;
    __syncthreads();
    mx = fmaxf(fmaxf(shm[0], shm[1]), fmaxf(shm[2], shm[3]));
    float e0 = __expf(y0 - mx);
    float e1 = v1 ? __expf(y1 - mx) : 0.f;
    float sm = e0 + e1;
    #pragma unroll
    for (int o = 32; o > 0; o >>= 1) sm += __shfl_xor(sm, o, 64);
    if (lane == 0) shs[wid] = sm;
    __syncthreads();
    sm = shs[0] + shs[1] + shs[2] + shs[3];
    float inv = 1.f / sm;
    attn[c * 480 + tid] = e0 * inv;
    if (v1) attn[c * 480 + tid + 256] = e1 * inv;
}

// ---------------- K4: T_hat = Vc @ sim^T ----------------
// M=196 (mask), N=480 (15 tiles), K=480 (30 steps); B[k][n] = sim[n][k]
__global__ __launch_bounds__(256) void k_that(const float* __restrict__ Vc,
                                              const float* __restrict__ sim,
                                              float* __restrict__ That) {
    __shared__ float As[16][68];
    __shared__ float Bs[16][36];
    int tid = threadIdx.x;
    int n0 = blockIdx.x * 32, m0 = blockIdx.y * 64;
    int ty = tid >> 4, tx = tid & 15;
    float a00=0,a01=0,a10=0,a11=0,a20=0,a21=0,a30=0,a31=0;
    int mrow = tid >> 2, kq = (tid & 3) * 4;
    for (int k0 = 0; k0 < 480; k0 += 16) {
        // A: Vc rows -> transposed
        {
            int m = m0 + mrow;
            float4 v = make_float4(0,0,0,0);
            if (m < N_TOK) v = *(const float4*)(Vc + m*480 + k0 + kq);
            As[kq+0][mrow] = v.x; As[kq+1][mrow] = v.y;
            As[kq+2][mrow] = v.z; As[kq+3][mrow] = v.w;
        }
        // B: sim rows (n0..n0+31) -> transposed
        if (tid < 128) {
            int nrow = tid >> 2, bkq = (tid & 3) * 4;
            float4 v = *(const float4*)(sim + (n0+nrow)*480 + k0 + bkq);
            Bs[bkq+0][nrow] = v.x; Bs[bkq+1][nrow] = v.y;
            Bs[bkq+2][nrow] = v.z; Bs[bkq+3][nrow] = v.w;
        }
        __syncthreads();
        #pragma unroll
        for (int kk = 0; kk < 16; ++kk) {
            float4 av = *(const float4*)&As[kk][ty*4];
            float2 bv = *(const float2*)&Bs[kk][tx*2];
            a00 = fmaf(av.x, bv.x, a00); a01 = fmaf(av.x, bv.y, a01);
            a10 = fmaf(av.y, bv.x, a10); a11 = fmaf(av.y, bv.y, a11);
            a20 = fmaf(av.z, bv.x, a20); a21 = fmaf(av.z, bv.y, a21);
            a30 = fmaf(av.w, bv.x, a30); a31 = fmaf(av.w, bv.y, a31);
        }
        __syncthreads();
    }
    int m = m0 + ty*4, n = n0 + tx*2;
    if (m   < N_TOK) *(float2*)(That + (m  )*480 + n) = make_float2(a00, a01);
    if (m+1 < N_TOK) *(float2*)(That + (m+1)*480 + n) = make_float2(a10, a11);
    if (m+2 < N_TOK) *(float2*)(That + (m+2)*480 + n) = make_float2(a20, a21);
    if (m+3 < N_TOK) *(float2*)(That + (m+3)*480 + n) = make_float2(a30, a31);
}

// ---------------- K5a: K/V projection + per-head stats ----------------
__global__ __launch_bounds__(256) void k_kv(const float* __restrict__ That,
                                            const float* __restrict__ Wk,
                                            const float* __restrict__ Wv,
                                            float2* __restrict__ KV,
                                            float* __restrict__ hs,
                                            float* __restrict__ hsq,
                                            unsigned* __restrict__ maxe,
                                            unsigned* __restrict__ nege) {
    int m = blockIdx.x * 256 + threadIdx.x;
    bool act = m < M_KV;
    int n = act ? (m % 196) : 0;
    int j = act ? (m / 196) : 0;
    float4 th = act ? *(const float4*)(That + n * 480 + 4 * j) : make_float4(0, 0, 0, 0);
    int lane = threadIdx.x & 63;
    #pragma unroll
    for (int h = 0; h < 4; ++h) {
        float kh = th.x * Wk[h] + th.y * Wk[4 + h] + th.z * Wk[8 + h] + th.w * Wk[12 + h];
        float vh = th.x * Wv[h] + th.y * Wv[4 + h] + th.z * Wv[8 + h] + th.w * Wv[12 + h];
        if (act) KV[h * M_KV + m] = make_float2(kh, vh);
        float su = act ? kh : 0.f;
        float sq = act ? kh * kh : 0.f;
        float mx = act ? kh : -INFINITY;
        float nm = act ? -kh : -INFINITY;
        #pragma unroll
        for (int o = 32; o > 0; o >>= 1) {
            su += __shfl_xor(su, o, 64);
            sq += __shfl_xor(sq, o, 64);
            mx = fmaxf(mx, __shfl_xor(mx, o, 64));
            nm = fmaxf(nm, __shfl_xor(nm, o, 64));
        }
        if (lane == 0) {
            atomicAdd(hs + h, su);
            atomicAdd(hsq + h, sq);
            atomicMax(maxe + h, enc_f(mx));
            atomicMax(nege + h, enc_f(nm));
        }
    }
}

// ---------------- K5b: per-(branch,head) beta table + analytic row max ------
__global__ __launch_bounds__(256) void k_qstats(const float* __restrict__ e0, const float* __restrict__ e1,
                                                const float* __restrict__ e2, const float* __restrict__ e3,
                                                const float* __restrict__ w0, const float* __restrict__ w1,
                                                const float* __restrict__ w2, const float* __restrict__ w3,
                                                const float* __restrict__ g2v,
                                                const float* __restrict__ hs, const float* __restrict__ hsq,
                                                const unsigned* __restrict__ maxe, const unsigned* __restrict__ nege,
                                                float* __restrict__ Btab, float* __restrict__ Mtab) {
    int rowid = blockIdx.x;
    int i = rowid >> 2, h = rowid & 3;
    const float* emb = (i == 0) ? e0 : (i == 1) ? e1 : (i == 2) ? e2 : e3;
    const float* Wq  = (i == 0) ? w0 : (i == 1) ? w1 : (i == 2) ? w2 : w3;
    int q = threadIdx.x;
    bool act = q < 196;
    float Q = 0.f;
    if (act) {
        Q = emb[q * 4] * Wq[h] + emb[q * 4 + 1] * Wq[4 + h] +
            emb[q * 4 + 2] * Wq[8 + h] + emb[q * 4 + 3] * Wq[12 + h];
    }
    float s = act ? Q : 0.f, s2 = act ? Q * Q : 0.f;
    #pragma unroll
    for (int o = 32; o > 0; o >>= 1) { s += __shfl_xor(s, o, 64); s2 += __shfl_xor(s2, o, 64); }
    __shared__ float shs[4], shs2[4];
    int wid = threadIdx.x >> 6, lane = threadIdx.x & 63;
    if (lane == 0) { shs[wid] = s; shs2[wid] = s2; }
    __syncthreads();
    float sumQ  = shs[0] + shs[1] + shs[2] + shs[3];
    float sumQ2 = shs2[0] + shs2[1] + shs2[2] + shs2[3];
    float Qbar = sumQ * (1.f / 196.f), Q2bar = sumQ2 * (1.f / 196.f);
    float Kbar = hs[h] * (1.f / (float)M_KV), K2bar = hsq[h] * (1.f / (float)M_KV);
    float mu = Qbar * Kbar;
    float var = Q2bar * K2bar - mu * mu;
    float sc = g2v[h] * rsqrtf(var + EPSN);
    float Kmax = dec_f(maxe[h]);
    float Kmin = -dec_f(nege[h]);
    if (act) {
        float b = Q * sc;
        Btab[rowid * 196 + q] = b;
        Mtab[rowid * 196 + q] = (b >= 0.f) ? b * Kmax : b * Kmin;
    }
}

// ---------------- K6: branch attention, split-k + split-q, reg-blocked ------
// grid: (16 chunks, 112 = 16 rows * 7 qgroups); block 256 = 4 waves
// wave handles 7 q's; lanes stride k within the 1470-key chunk; KV read from L2.
#define CHUNKS 16
#define CH 1470
__global__ __launch_bounds__(256) void k_branch(const float2* __restrict__ KV,
                                                const float* __restrict__ Btab,
                                                const float* __restrict__ Mtab,
                                                float* __restrict__ Lacc,
                                                float* __restrict__ Cacc) {
    int rq = blockIdx.y;
    int row = rq / 7, qg = rq % 7;
    int h = row & 3;
    int wid = threadIdx.x >> 6, lane = threadIdx.x & 63;
    int qbase = qg * 28 + wid * 7;           // 7 q's per wave
    float beta[7], negM[7];
    #pragma unroll
    for (int j = 0; j < 7; ++j) {
        beta[j] = Btab[row * 196 + qbase + j];
        negM[j] = -Mtab[row * 196 + qbase + j];
    }
    const float2* kvp = KV + h * M_KV;
    int kbase = blockIdx.x * CH;
    int kend = kbase + CH;
    float l[7] = {0,0,0,0,0,0,0};
    float a[7] = {0,0,0,0,0,0,0};
    for (int k = kbase + lane; k < kend; k += 64) {
        float2 p = kvp[k];
        #pragma unroll
        for (int j = 0; j < 7; ++j) {
            float x = __expf(fmaf(beta[j], p.x, negM[j]));
            l[j] += x;
            a[j] = fmaf(x, p.y, a[j]);
        }
    }
    #pragma unroll
    for (int j = 0; j < 7; ++j) {
        float lv = l[j], av = a[j];
        #pragma unroll
        for (int o = 32; o > 0; o >>= 1) { lv += __shfl_xor(lv, o, 64); av += __shfl_xor(av, o, 64); }
        if (lane == 0) {
            atomicAdd(Lacc + row * 196 + qbase + j, lv);
            atomicAdd(Cacc + row * 196 + qbase + j, av);
        }
    }
}

// ---------------- K7: finalize: c = acc/l, out = c @ Wo ----------------
__global__ __launch_bounds__(256) void k_final(const float* __restrict__ Lacc,
                                               const float* __restrict__ Cacc,
                                               const float* __restrict__ o0, const float* __restrict__ o1,
                                               const float* __restrict__ o2, const float* __restrict__ o3,
                                               float* __restrict__ out) {
    int i = blockIdx.x;
    int q = threadIdx.x;
    if (q >= 196) return;
    const float* Wo = (i == 0) ? o0 : (i == 1) ? o1 : (i == 2) ? o2 : o3;
    float c[4];
    #pragma unroll
    for (int h = 0; h < 4; ++h) {
        int idx = (i * 4 + h) * 196 + q;
        c[h] = Cacc[idx] / Lacc[idx];
    }
    float4 o;
    o.x = c[0] * Wo[0] + c[1] * Wo[4] + c[2] * Wo[8]  + c[3] * Wo[12];
    o.y = c[0] * Wo[1] + c[1] * Wo[5] + c[2] * Wo[9]  + c[3] * Wo[13];
    o.z = c[0] * Wo[2] + c[1] * Wo[6] + c[2] * Wo[10] + c[3] * Wo[14];
    o.w = c[0] * Wo[3] + c[1] * Wo[7] + c[2] * Wo[11] + c[3] * Wo[15];
    *(float4*)(out + i * 784 + q * 4) = o;
}

extern "C" void kernel_launch(void* const* d_in, const int* in_sizes, int n_in,
                              void* d_out, int out_size, void* d_ws, size_t ws_size,
                              hipStream_t stream) {
    const float* emb1 = (const float*)d_in[0];
    const float* emb2 = (const float*)d_in[1];
    const float* emb3 = (const float*)d_in[2];
    const float* emb4 = (const float*)d_in[3];
    const float* embC = (const float*)d_in[4];
    const float* WqC  = (const float*)d_in[5];
    const float* WkC  = (const float*)d_in[6];
    const float* WvC  = (const float*)d_in[7];
    const float* Wq1  = (const float*)d_in[8];
    const float* Wq2  = (const float*)d_in[9];
    const float* Wq3  = (const float*)d_in[10];
    const float* Wq4  = (const float*)d_in[11];
    const float* Wk   = (const float*)d_in[12];
    const float* Wv   = (const float*)d_in[13];
    const float* Wo1  = (const float*)d_in[14];
    const float* Wo2  = (const float*)d_in[15];
    const float* Wo3  = (const float*)d_in[16];
    const float* Wo4  = (const float*)d_in[17];
    const float* g1   = (const float*)d_in[18];
    const float* g2   = (const float*)d_in[20];
    float* ws = (float*)d_ws;
    float* out = (float*)d_out;

    // zero accumulators (ws poisoned 0xAA once; we must re-zero every call)
    hipMemsetAsync(ws + ZERO_OFF, 0, ZERO_CNT * sizeof(float), stream);

    k_qkv<<<dim3(15, 4, 3), 256, 0, stream>>>(embC, WqC, WkC, WvC, ws);
    k_attn<<<dim3(15, 8), 256, 0, stream>>>(ws + OFF_QC, ws + OFF_KC, ws + OFF_ATTN, ws + OFF_S1);
    k_softmax<<<480, 256, 0, stream>>>(ws + OFF_ATTN, ws + OFF_S1, g1);
    k_that<<<dim3(15, 4), 256, 0, stream>>>(ws + OFF_VC, ws + OFF_ATTN, ws + OFF_THAT);
    k_kv<<<92, 256, 0, stream>>>(ws + OFF_THAT, Wk, Wv, (float2*)(ws + OFF_KV),
                                 ws + OFF_HS, ws + OFF_HSQ,
                                 (unsigned*)(ws + OFF_MAXE), (unsigned*)(ws + OFF_NEGE));
    k_qstats<<<16, 256, 0, stream>>>(emb1, emb2, emb3, emb4, Wq1, Wq2, Wq3, Wq4, g2,
                                     ws + OFF_HS, ws + OFF_HSQ,
                                     (const unsigned*)(ws + OFF_MAXE), (const unsigned*)(ws + OFF_NEGE),
                                     ws + OFF_BTAB, ws + OFF_MTAB);
    k_branch<<<dim3(CHUNKS, 112), 256, 0, stream>>>((const float2*)(ws + OFF_KV),
                                                    ws + OFF_BTAB, ws + OFF_MTAB,
                                                    ws + OFF_LACC, ws + OFF_CACC);
    k_final<<<4, 256, 0, stream>>>(ws + OFF_LACC, ws + OFF_CACC, Wo1, Wo2, Wo3, Wo4, out);
}

// Round 4
// 110.147 us; speedup vs baseline: 2.4896x; 1.7070x over previous
//
#include <hip/hip_runtime.h>
#include <hip/hip_bf16.h>
#include <math.h>

// Problem constants
#define N_TOK 196
#define C_DIM 480
#define M_KV  23520      // (C/4)*N
#define EPSN  1e-3f
#define LOG2E 1.44269504088896340736f

// Workspace layout (in floats)
#define OFF_QC    0
#define OFF_KC    94080
#define OFF_VC    188160
#define OFF_ATTN  282240   // 480*480 = 230400, becomes sim in-place; dead after k_that
#define OFF_THAT  512640   // 196*480
#define OFF_KV    606720   // float2[4*23520] = 188160 floats
#define OFF_BTAB  794880   // 16*196  (stores beta*log2e)
#define OFF_MTAB  798016   // 16*196  (stores rowmax*log2e)
#define OFF_SPART 801152   // 120*2 per-block [sum,sumsq] partials of attn
#define OFF_KPART 801408   // [4 stats][4 heads][96] = 1536 floats
// slabs alias the dead attn region (k_branch runs after k_that)
#define OFF_LSLAB 282240   // 8*16*196 = 25088
#define OFF_CSLAB 307328   // 8*16*196 = 25088 (end 332416 < OFF_THAT)

__device__ __forceinline__ float fast_exp2(float x) {
#if __has_builtin(__builtin_amdgcn_exp2f)
    return __builtin_amdgcn_exp2f(x);
#else
    return exp2f(x);
#endif
}

// ============ GEMM tiles: 64 (M) x 32 (N), 256 threads, 4x2 per thread ======

// ---------------- K1: Qc/Kc/Vc = emb_C @ {Wq_C,Wk_C,Wv_C} ----------------
__global__ __launch_bounds__(256) void k_qkv(const float* __restrict__ embC,
                                             const float* __restrict__ Wq,
                                             const float* __restrict__ Wk,
                                             const float* __restrict__ Wv,
                                             float* __restrict__ ws) {
    int zi = blockIdx.z;
    const float* W = (zi == 0) ? Wq : (zi == 1 ? Wk : Wv);
    float* out = ws + zi * 94080;
    __shared__ float As[16][68];
    __shared__ float Bs[16][36];
    int tid = threadIdx.x;
    int n0 = blockIdx.x * 32, m0 = blockIdx.y * 64;
    int ty = tid >> 4, tx = tid & 15;
    float a00=0,a01=0,a10=0,a11=0,a20=0,a21=0,a30=0,a31=0;
    int mrow = tid >> 2, kq = (tid & 3) * 4;
    for (int k0 = 0; k0 < 480; k0 += 16) {
        {
            int m = m0 + mrow;
            float4 v = make_float4(0,0,0,0);
            if (m < N_TOK) v = *(const float4*)(embC + m*480 + k0 + kq);
            As[kq+0][mrow] = v.x; As[kq+1][mrow] = v.y;
            As[kq+2][mrow] = v.z; As[kq+3][mrow] = v.w;
        }
        if (tid < 128) {
            int kk = tid >> 3, nq = (tid & 7) * 4;
            float4 v = *(const float4*)(W + (k0+kk)*480 + n0 + nq);
            *(float4*)&Bs[kk][nq] = v;
        }
        __syncthreads();
        #pragma unroll
        for (int kk = 0; kk < 16; ++kk) {
            float4 av = *(const float4*)&As[kk][ty*4];
            float2 bv = *(const float2*)&Bs[kk][tx*2];
            a00 = fmaf(av.x, bv.x, a00); a01 = fmaf(av.x, bv.y, a01);
            a10 = fmaf(av.y, bv.x, a10); a11 = fmaf(av.y, bv.y, a11);
            a20 = fmaf(av.z, bv.x, a20); a21 = fmaf(av.z, bv.y, a21);
            a30 = fmaf(av.w, bv.x, a30); a31 = fmaf(av.w, bv.y, a31);
        }
        __syncthreads();
    }
    int m = m0 + ty*4, n = n0 + tx*2;
    if (m   < N_TOK) *(float2*)(out + (m  )*480 + n) = make_float2(a00, a01);
    if (m+1 < N_TOK) *(float2*)(out + (m+1)*480 + n) = make_float2(a10, a11);
    if (m+2 < N_TOK) *(float2*)(out + (m+2)*480 + n) = make_float2(a20, a21);
    if (m+3 < N_TOK) *(float2*)(out + (m+3)*480 + n) = make_float2(a30, a31);
}

// ---------------- K2: attn = Qc^T @ Kc  (+ per-block sum/sumsq partials) ----
// NOTE: m ranges to 511 (8 tiles of 64 over 480 rows) — phantom rows MUST be
// zero-filled in As (they feed the psi1 stats) and store-guarded (round-3 bug).
__global__ __launch_bounds__(256) void k_attn(const float* __restrict__ Qc,
                                              const float* __restrict__ Kc,
                                              float* __restrict__ attn,
                                              float* __restrict__ Spart) {
    __shared__ float As[16][68];
    __shared__ float Bs[16][36];
    __shared__ float sha[4], shb[4];
    int tid = threadIdx.x;
    int n0 = blockIdx.x * 32, m0 = blockIdx.y * 64;
    int ty = tid >> 4, tx = tid & 15;
    float a00=0,a01=0,a10=0,a11=0,a20=0,a21=0,a30=0,a31=0;
    for (int k0 = 0; k0 < 208; k0 += 16) {
        {
            int kk = tid >> 4, mq = (tid & 15) * 4;
            float4 v = make_float4(0,0,0,0);
            if (k0+kk < N_TOK && m0+mq < 480)
                v = *(const float4*)(Qc + (k0+kk)*480 + m0 + mq);
            *(float4*)&As[kk][mq] = v;
        }
        if (tid < 128) {
            int kk = tid >> 3, nq = (tid & 7) * 4;
            float4 v = make_float4(0,0,0,0);
            if (k0+kk < N_TOK) v = *(const float4*)(Kc + (k0+kk)*480 + n0 + nq);
            *(float4*)&Bs[kk][nq] = v;
        }
        __syncthreads();
        #pragma unroll
        for (int kk = 0; kk < 16; ++kk) {
            float4 av = *(const float4*)&As[kk][ty*4];
            float2 bv = *(const float2*)&Bs[kk][tx*2];
            a00 = fmaf(av.x, bv.x, a00); a01 = fmaf(av.x, bv.y, a01);
            a10 = fmaf(av.y, bv.x, a10); a11 = fmaf(av.y, bv.y, a11);
            a20 = fmaf(av.z, bv.x, a20); a21 = fmaf(av.z, bv.y, a21);
            a30 = fmaf(av.w, bv.x, a30); a31 = fmaf(av.w, bv.y, a31);
        }
        __syncthreads();
    }
    int m = m0 + ty*4, n = n0 + tx*2;
    if (m   < 480) *(float2*)(attn + (m  )*480 + n) = make_float2(a00, a01);
    if (m+1 < 480) *(float2*)(attn + (m+1)*480 + n) = make_float2(a10, a11);
    if (m+2 < 480) *(float2*)(attn + (m+2)*480 + n) = make_float2(a20, a21);
    if (m+3 < 480) *(float2*)(attn + (m+3)*480 + n) = make_float2(a30, a31);
    // stats: phantom rows have exactly-zero accumulators (As zero-filled)
    float ls = a00+a01+a10+a11+a20+a21+a30+a31;
    float lq = a00*a00+a01*a01+a10*a10+a11*a11+a20*a20+a21*a21+a30*a30+a31*a31;
    #pragma unroll
    for (int o = 32; o > 0; o >>= 1) { ls += __shfl_xor(ls, o, 64); lq += __shfl_xor(lq, o, 64); }
    int wid = tid >> 6, lane = tid & 63;
    if (lane == 0) { sha[wid] = ls; shb[wid] = lq; }
    __syncthreads();
    if (tid == 0) {
        int bid = blockIdx.y * gridDim.x + blockIdx.x;
        Spart[bid*2]   = sha[0] + sha[1] + sha[2] + sha[3];
        Spart[bid*2+1] = shb[0] + shb[1] + shb[2] + shb[3];
    }
}

// ---------------- K3: per-row softmax of attn * s ----------------
__global__ __launch_bounds__(256) void k_softmax(float* __restrict__ attn,
                                                 const float* __restrict__ Spart,
                                                 const float* __restrict__ g1) {
    int c = blockIdx.x;
    int tid = threadIdx.x;
    int wid = tid >> 6, lane = tid & 63;
    __shared__ float pr[4][2];
    __shared__ float shm[4], shs[4];
    float ps = 0.f, pq = 0.f;
    if (tid < 120) { ps = Spart[tid*2]; pq = Spart[tid*2+1]; }
    #pragma unroll
    for (int o = 32; o > 0; o >>= 1) { ps += __shfl_xor(ps, o, 64); pq += __shfl_xor(pq, o, 64); }
    if (lane == 0) { pr[wid][0] = ps; pr[wid][1] = pq; }
    __syncthreads();
    float S  = pr[0][0] + pr[1][0] + pr[2][0] + pr[3][0];
    float SQ = pr[0][1] + pr[1][1] + pr[2][1] + pr[3][1];
    const float invCC = 1.f / (480.f * 480.f);
    float mean = S * invCC;
    float var  = SQ * invCC - mean * mean;
    float s = g1[0] * rsqrtf(var + EPSN);
    float y0 = attn[c * 480 + tid] * s;
    bool v1 = tid < 224;
    float y1 = v1 ? attn[c * 480 + tid + 256] * s : -INFINITY;
    float mx = fmaxf(y0, y1);
    #pragma unroll
    for (int o = 32; o > 0; o >>= 1) mx = fmaxf(mx, __shfl_xor(mx, o, 64));
    if (lane == 0) shm[wid] = mx;
    __syncthreads();
    mx = fmaxf(fmaxf(shm[0], shm[1]), fmaxf(shm[2], shm[3]));
    float e0 = __expf(y0 - mx);
    float e1 = v1 ? __expf(y1 - mx) : 0.f;
    float sm = e0 + e1;
    #pragma unroll
    for (int o = 32; o > 0; o >>= 1) sm += __shfl_xor(sm, o, 64);
    if (lane == 0) shs[wid] = sm;
    __syncthreads();
    sm = shs[0] + shs[1] + shs[2] + shs[3];
    float inv = 1.f / sm;
    attn[c * 480 + tid] = e0 * inv;
    if (v1) attn[c * 480 + tid + 256] = e1 * inv;
}

// ---------------- K4: T_hat = Vc @ sim^T ----------------
__global__ __launch_bounds__(256) void k_that(const float* __restrict__ Vc,
                                              const float* __restrict__ sim,
                                              float* __restrict__ That) {
    __shared__ float As[16][68];
    __shared__ float Bs[16][36];
    int tid = threadIdx.x;
    int n0 = blockIdx.x * 32, m0 = blockIdx.y * 64;
    int ty = tid >> 4, tx = tid & 15;
    float a00=0,a01=0,a10=0,a11=0,a20=0,a21=0,a30=0,a31=0;
    int mrow = tid >> 2, kq = (tid & 3) * 4;
    for (int k0 = 0; k0 < 480; k0 += 16) {
        {
            int m = m0 + mrow;
            float4 v = make_float4(0,0,0,0);
            if (m < N_TOK) v = *(const float4*)(Vc + m*480 + k0 + kq);
            As[kq+0][mrow] = v.x; As[kq+1][mrow] = v.y;
            As[kq+2][mrow] = v.z; As[kq+3][mrow] = v.w;
        }
        if (tid < 128) {
            int nrow = tid >> 2, bkq = (tid & 3) * 4;
            float4 v = *(const float4*)(sim + (n0+nrow)*480 + k0 + bkq);
            Bs[bkq+0][nrow] = v.x; Bs[bkq+1][nrow] = v.y;
            Bs[bkq+2][nrow] = v.z; Bs[bkq+3][nrow] = v.w;
        }
        __syncthreads();
        #pragma unroll
        for (int kk = 0; kk < 16; ++kk) {
            float4 av = *(const float4*)&As[kk][ty*4];
            float2 bv = *(const float2*)&Bs[kk][tx*2];
            a00 = fmaf(av.x, bv.x, a00); a01 = fmaf(av.x, bv.y, a01);
            a10 = fmaf(av.y, bv.x, a10); a11 = fmaf(av.y, bv.y, a11);
            a20 = fmaf(av.z, bv.x, a20); a21 = fmaf(av.z, bv.y, a21);
            a30 = fmaf(av.w, bv.x, a30); a31 = fmaf(av.w, bv.y, a31);
        }
        __syncthreads();
    }
    int m = m0 + ty*4, n = n0 + tx*2;
    if (m   < N_TOK) *(float2*)(That + (m  )*480 + n) = make_float2(a00, a01);
    if (m+1 < N_TOK) *(float2*)(That + (m+1)*480 + n) = make_float2(a10, a11);
    if (m+2 < N_TOK) *(float2*)(That + (m+2)*480 + n) = make_float2(a20, a21);
    if (m+3 < N_TOK) *(float2*)(That + (m+3)*480 + n) = make_float2(a30, a31);
}

// ---------------- K5a: K/V projection + per-block stat partials ----------------
// kpart layout: [stat 0..3][head 0..3][96 block slots]; stats: sum, sumsq, max, min
__global__ __launch_bounds__(256) void k_kv(const float* __restrict__ That,
                                            const float* __restrict__ Wk,
                                            const float* __restrict__ Wv,
                                            float2* __restrict__ KV,
                                            float* __restrict__ kpart) {
    int m = blockIdx.x * 256 + threadIdx.x;
    bool act = m < M_KV;
    int n = act ? (m % 196) : 0;
    int j = act ? (m / 196) : 0;
    float4 th = act ? *(const float4*)(That + n * 480 + 4 * j) : make_float4(0, 0, 0, 0);
    int wid = threadIdx.x >> 6, lane = threadIdx.x & 63;
    __shared__ float wpart[4][4][4];  // [wave][head][stat]
    #pragma unroll
    for (int h = 0; h < 4; ++h) {
        float kh = th.x * Wk[h] + th.y * Wk[4 + h] + th.z * Wk[8 + h] + th.w * Wk[12 + h];
        float vh = th.x * Wv[h] + th.y * Wv[4 + h] + th.z * Wv[8 + h] + th.w * Wv[12 + h];
        if (act) KV[h * M_KV + m] = make_float2(kh, vh);
        float su = act ? kh : 0.f;
        float sq = act ? kh * kh : 0.f;
        float mx = act ? kh : -INFINITY;
        float mn = act ? kh : INFINITY;
        #pragma unroll
        for (int o = 32; o > 0; o >>= 1) {
            su += __shfl_xor(su, o, 64);
            sq += __shfl_xor(sq, o, 64);
            mx = fmaxf(mx, __shfl_xor(mx, o, 64));
            mn = fminf(mn, __shfl_xor(mn, o, 64));
        }
        if (lane == 0) {
            wpart[wid][h][0] = su; wpart[wid][h][1] = sq;
            wpart[wid][h][2] = mx; wpart[wid][h][3] = mn;
        }
    }
    __syncthreads();
    if (threadIdx.x < 16) {
        int h = threadIdx.x & 3, st = threadIdx.x >> 2;
        float v0 = wpart[0][h][st], v1 = wpart[1][h][st], v2 = wpart[2][h][st], v3 = wpart[3][h][st];
        float r;
        if (st < 2)       r = v0 + v1 + v2 + v3;
        else if (st == 2) r = fmaxf(fmaxf(v0, v1), fmaxf(v2, v3));
        else              r = fminf(fminf(v0, v1), fminf(v2, v3));
        kpart[st * 384 + h * 96 + blockIdx.x] = r;
    }
}

// ---------------- K5b: per-(branch,head) beta/M tables (log2e folded) -------
__global__ __launch_bounds__(256) void k_qstats(const float* __restrict__ e0, const float* __restrict__ e1,
                                                const float* __restrict__ e2, const float* __restrict__ e3,
                                                const float* __restrict__ w0, const float* __restrict__ w1,
                                                const float* __restrict__ w2, const float* __restrict__ w3,
                                                const float* __restrict__ g2v,
                                                const float* __restrict__ kpart,
                                                float* __restrict__ Btab, float* __restrict__ Mtab) {
    int rowid = blockIdx.x;
    int i = rowid >> 2, h = rowid & 3;
    const float* emb = (i == 0) ? e0 : (i == 1) ? e1 : (i == 2) ? e2 : e3;
    const float* Wq  = (i == 0) ? w0 : (i == 1) ? w1 : (i == 2) ? w2 : w3;
    int q = threadIdx.x;
    int wid = q >> 6, lane = q & 63;
    bool act = q < 196;
    float Q = 0.f;
    if (act) {
        Q = emb[q * 4] * Wq[h] + emb[q * 4 + 1] * Wq[4 + h] +
            emb[q * 4 + 2] * Wq[8 + h] + emb[q * 4 + 3] * Wq[12 + h];
    }
    float s = act ? Q : 0.f, s2 = act ? Q * Q : 0.f;
    #pragma unroll
    for (int o = 32; o > 0; o >>= 1) { s += __shfl_xor(s, o, 64); s2 += __shfl_xor(s2, o, 64); }
    // K-stat partial reduce (92 slots)
    float ks = 0.f, kq2 = 0.f, km = -INFINITY, kn = INFINITY;
    if (q < 92) {
        ks  = kpart[0 * 384 + h * 96 + q];
        kq2 = kpart[1 * 384 + h * 96 + q];
        km  = kpart[2 * 384 + h * 96 + q];
        kn  = kpart[3 * 384 + h * 96 + q];
    }
    #pragma unroll
    for (int o = 32; o > 0; o >>= 1) {
        ks += __shfl_xor(ks, o, 64); kq2 += __shfl_xor(kq2, o, 64);
        km = fmaxf(km, __shfl_xor(km, o, 64)); kn = fminf(kn, __shfl_xor(kn, o, 64));
    }
    __shared__ float shs[4], shs2[4], red[4][4];
    if (lane == 0) {
        shs[wid] = s; shs2[wid] = s2;
        red[wid][0] = ks; red[wid][1] = kq2; red[wid][2] = km; red[wid][3] = kn;
    }
    __syncthreads();
    float sumQ  = shs[0] + shs[1] + shs[2] + shs[3];
    float sumQ2 = shs2[0] + shs2[1] + shs2[2] + shs2[3];
    float Ksum  = red[0][0] + red[1][0] + red[2][0] + red[3][0];
    float Ksq   = red[0][1] + red[1][1] + red[2][1] + red[3][1];
    float Kmax  = fmaxf(fmaxf(red[0][2], red[1][2]), fmaxf(red[2][2], red[3][2]));
    float Kmin  = fminf(fminf(red[0][3], red[1][3]), fminf(red[2][3], red[3][3]));
    float Qbar = sumQ * (1.f / 196.f), Q2bar = sumQ2 * (1.f / 196.f);
    float Kbar = Ksum * (1.f / (float)M_KV), K2bar = Ksq * (1.f / (float)M_KV);
    float mu = Qbar * Kbar;
    float var = Q2bar * K2bar - mu * mu;
    float sc = g2v[h] * rsqrtf(var + EPSN);
    if (act) {
        float b = Q * sc;
        float M = (b >= 0.f) ? b * Kmax : b * Kmin;
        Btab[rowid * 196 + q] = b * LOG2E;
        Mtab[rowid * 196 + q] = M * LOG2E;
    }
}

// ---------------- K6: branch attention, split-k slabs, no atomics ----------
#define CHUNKS 8
#define CH 2940
__global__ __launch_bounds__(256) void k_branch(const float2* __restrict__ KV,
                                                const float* __restrict__ Btab,
                                                const float* __restrict__ Mtab,
                                                float* __restrict__ Lslab,
                                                float* __restrict__ Cslab) {
    int rq = blockIdx.y;
    int row = rq / 7, qg = rq % 7;
    int h = row & 3;
    int wid = threadIdx.x >> 6, lane = threadIdx.x & 63;
    int qbase = qg * 28 + wid * 7;
    float B2[7], nM2[7];
    #pragma unroll
    for (int j = 0; j < 7; ++j) {
        B2[j]  = Btab[row * 196 + qbase + j];
        nM2[j] = -Mtab[row * 196 + qbase + j];
    }
    const float2* kvp = KV + h * M_KV;
    int kbase = blockIdx.x * CH;
    int kend = kbase + CH;
    float l[7] = {0,0,0,0,0,0,0};
    float a[7] = {0,0,0,0,0,0,0};
    for (int k = kbase + lane; k < kend; k += 64) {
        float2 p = kvp[k];
        #pragma unroll
        for (int j = 0; j < 7; ++j) {
            float x = fast_exp2(fmaf(B2[j], p.x, nM2[j]));
            l[j] += x;
            a[j] = fmaf(x, p.y, a[j]);
        }
    }
    int sbase = (blockIdx.x * 16 + row) * 196 + qbase;
    #pragma unroll
    for (int j = 0; j < 7; ++j) {
        float lv = l[j], av = a[j];
        #pragma unroll
        for (int o = 32; o > 0; o >>= 1) { lv += __shfl_xor(lv, o, 64); av += __shfl_xor(av, o, 64); }
        if (lane == 0) {
            Lslab[sbase + j] = lv;
            Cslab[sbase + j] = av;
        }
    }
}

// ---------------- K7: finalize: sum slabs, c = C/L, out = c @ Wo ------------
__global__ __launch_bounds__(256) void k_final(const float* __restrict__ Lslab,
                                               const float* __restrict__ Cslab,
                                               const float* __restrict__ o0, const float* __restrict__ o1,
                                               const float* __restrict__ o2, const float* __restrict__ o3,
                                               float* __restrict__ out) {
    int i = blockIdx.x;
    int q = threadIdx.x;
    if (q >= 196) return;
    const float* Wo = (i == 0) ? o0 : (i == 1) ? o1 : (i == 2) ? o2 : o3;
    float c[4];
    #pragma unroll
    for (int h = 0; h < 4; ++h) {
        float L = 0.f, Cc = 0.f;
        #pragma unroll
        for (int ch = 0; ch < CHUNKS; ++ch) {
            int idx = (ch * 16 + i * 4 + h) * 196 + q;
            L  += Lslab[idx];
            Cc += Cslab[idx];
        }
        c[h] = Cc / L;
    }
    float4 o;
    o.x = c[0] * Wo[0] + c[1] * Wo[4] + c[2] * Wo[8]  + c[3] * Wo[12];
    o.y = c[0] * Wo[1] + c[1] * Wo[5] + c[2] * Wo[9]  + c[3] * Wo[13];
    o.z = c[0] * Wo[2] + c[1] * Wo[6] + c[2] * Wo[10] + c[3] * Wo[14];
    o.w = c[0] * Wo[3] + c[1] * Wo[7] + c[2] * Wo[11] + c[3] * Wo[15];
    *(float4*)(out + i * 784 + q * 4) = o;
}

extern "C" void kernel_launch(void* const* d_in, const int* in_sizes, int n_in,
                              void* d_out, int out_size, void* d_ws, size_t ws_size,
                              hipStream_t stream) {
    const float* emb1 = (const float*)d_in[0];
    const float* emb2 = (const float*)d_in[1];
    const float* emb3 = (const float*)d_in[2];
    const float* emb4 = (const float*)d_in[3];
    const float* embC = (const float*)d_in[4];
    const float* WqC  = (const float*)d_in[5];
    const float* WkC  = (const float*)d_in[6];
    const float* WvC  = (const float*)d_in[7];
    const float* Wq1  = (const float*)d_in[8];
    const float* Wq2  = (const float*)d_in[9];
    const float* Wq3  = (const float*)d_in[10];
    const float* Wq4  = (const float*)d_in[11];
    const float* Wk   = (const float*)d_in[12];
    const float* Wv   = (const float*)d_in[13];
    const float* Wo1  = (const float*)d_in[14];
    const float* Wo2  = (const float*)d_in[15];
    const float* Wo3  = (const float*)d_in[16];
    const float* Wo4  = (const float*)d_in[17];
    const float* g1   = (const float*)d_in[18];
    const float* g2   = (const float*)d_in[20];
    float* ws = (float*)d_ws;
    float* out = (float*)d_out;

    k_qkv<<<dim3(15, 4, 3), 256, 0, stream>>>(embC, WqC, WkC, WvC, ws);
    k_attn<<<dim3(15, 8), 256, 0, stream>>>(ws + OFF_QC, ws + OFF_KC, ws + OFF_ATTN, ws + OFF_SPART);
    k_softmax<<<480, 256, 0, stream>>>(ws + OFF_ATTN, ws + OFF_SPART, g1);
    k_that<<<dim3(15, 4), 256, 0, stream>>>(ws + OFF_VC, ws + OFF_ATTN, ws + OFF_THAT);
    k_kv<<<92, 256, 0, stream>>>(ws + OFF_THAT, Wk, Wv, (float2*)(ws + OFF_KV), ws + OFF_KPART);
    k_qstats<<<16, 256, 0, stream>>>(emb1, emb2, emb3, emb4, Wq1, Wq2, Wq3, Wq4, g2,
                                     ws + OFF_KPART, ws + OFF_BTAB, ws + OFF_MTAB);
    k_branch<<<dim3(CHUNKS, 112), 256, 0, stream>>>((const float2*)(ws + OFF_KV),
                                                    ws + OFF_BTAB, ws + OFF_MTAB,
                                                    ws + OFF_LSLAB, ws + OFF_CSLAB);
    k_final<<<4, 256, 0, stream>>>(ws + OFF_LSLAB, ws + OFF_CSLAB, Wo1, Wo2, Wo3, Wo4, out);
}